// Round 2
// baseline (70.252 us; speedup 1.0000x reference)
//
#include <hip/hip_runtime.h>

// Complex BatchNorm (training whitening), z:[B=32, N=C*H*W, 2] fp32.
// Two-position-per-thread (float4) version, explicit two-pass:
//   pass 1: streaming raw moments (Sx,Sy,Sxx,Sxy,Syy) -- no sample retention
//   pass 2: re-read (L2/L3-hit) and apply fused whitening+gamma+beta.
// Low VGPR -> high occupancy; 16 B/lane loads -> max coalescing.

constexpr int BATCH = 32;

__global__ __launch_bounds__(256) void cbn_kernel(
    const float4* __restrict__ z,
    const float* __restrict__ gamma,
    const float* __restrict__ beta,
    float4* __restrict__ out,
    int N2)   // N2 = N/2 float4 "pair" positions
{
    int i = blockIdx.x * blockDim.x + threadIdx.x;
    if (i >= N2) return;

    // ---- pass 1: raw moments for the two positions in this float4 lane ----
    float sx0 = 0.f, sy0 = 0.f, sxx0 = 0.f, sxy0 = 0.f, syy0 = 0.f;
    float sx1 = 0.f, sy1 = 0.f, sxx1 = 0.f, sxy1 = 0.f, syy1 = 0.f;
#pragma unroll
    for (int b = 0; b < BATCH; ++b) {
        float4 v = z[(size_t)b * N2 + i];
        sx0 += v.x; sy0 += v.y;
        sxx0 = fmaf(v.x, v.x, sxx0);
        sxy0 = fmaf(v.x, v.y, sxy0);
        syy0 = fmaf(v.y, v.y, syy0);
        sx1 += v.z; sy1 += v.w;
        sxx1 = fmaf(v.z, v.z, sxx1);
        sxy1 = fmaf(v.z, v.w, sxy1);
        syy1 = fmaf(v.w, v.w, syy1);
    }

    const float invB  = 1.0f / BATCH;
    const float invB1 = 1.0f / (BATCH - 1);

    float g00 = gamma[0], g01 = gamma[1], g10 = gamma[2], g11 = gamma[3];
    float be0 = beta[0], be1 = beta[1];

    // position 0
    float mx0 = sx0 * invB, my0 = sy0 * invB;
    float cxx0 = (sxx0 - BATCH * mx0 * mx0) * invB1;
    float cxy0 = (sxy0 - BATCH * mx0 * my0) * invB1;
    float cyy0 = (syy0 - BATCH * my0 * my0) * invB1;
    float s0 = sqrtf(cxx0 * cyy0 - cxy0 * cxy0);
    float rt0 = 1.0f / sqrtf(cxx0 + cyy0 + 2.0f * s0);
    float a00_0 = (cxx0 + s0) * rt0, a01_0 = cxy0 * rt0, a11_0 = (cyy0 + s0) * rt0;
    float c00_0 = g00 * a00_0 + g01 * a01_0;
    float c01_0 = g00 * a01_0 + g01 * a11_0;
    float c10_0 = g10 * a00_0 + g11 * a01_0;
    float c11_0 = g10 * a01_0 + g11 * a11_0;

    // position 1
    float mx1 = sx1 * invB, my1 = sy1 * invB;
    float cxx1 = (sxx1 - BATCH * mx1 * mx1) * invB1;
    float cxy1 = (sxy1 - BATCH * mx1 * my1) * invB1;
    float cyy1 = (syy1 - BATCH * my1 * my1) * invB1;
    float s1 = sqrtf(cxx1 * cyy1 - cxy1 * cxy1);
    float rt1 = 1.0f / sqrtf(cxx1 + cyy1 + 2.0f * s1);
    float a00_1 = (cxx1 + s1) * rt1, a01_1 = cxy1 * rt1, a11_1 = (cyy1 + s1) * rt1;
    float c00_1 = g00 * a00_1 + g01 * a01_1;
    float c01_1 = g00 * a01_1 + g01 * a11_1;
    float c10_1 = g10 * a00_1 + g11 * a01_1;
    float c11_1 = g10 * a01_1 + g11 * a11_1;

    // ---- pass 2: re-read (cache-hit) and apply ----
#pragma unroll
    for (int b = 0; b < BATCH; ++b) {
        float4 v = z[(size_t)b * N2 + i];
        float dx0 = v.x - mx0, dy0 = v.y - my0;
        float dx1 = v.z - mx1, dy1 = v.w - my1;
        float4 o;
        o.x = fmaf(c00_0, dx0, fmaf(c01_0, dy0, be0));
        o.y = fmaf(c10_0, dx0, fmaf(c11_0, dy0, be1));
        o.z = fmaf(c00_1, dx1, fmaf(c01_1, dy1, be0));
        o.w = fmaf(c10_1, dx1, fmaf(c11_1, dy1, be1));
        out[(size_t)b * N2 + i] = o;
    }
}

extern "C" void kernel_launch(void* const* d_in, const int* in_sizes, int n_in,
                              void* d_out, int out_size, void* d_ws, size_t ws_size,
                              hipStream_t stream) {
    const float4* z    = (const float4*)d_in[0];
    const float* gamma = (const float*)d_in[1];
    const float* beta  = (const float*)d_in[2];
    float4* out = (float4*)d_out;

    // in_sizes[0] = B * N * 2; pairs of positions: N2 = N/2 = total/(B*4)
    int N2 = in_sizes[0] / (BATCH * 4);

    dim3 block(256);
    dim3 grid((N2 + block.x - 1) / block.x);
    hipLaunchKernelGGL(cbn_kernel, grid, block, 0, stream, z, gamma, beta, out, N2);
}

// Round 3
// 54.048 us; speedup vs baseline: 1.2998x; 1.2998x over previous
//
#include <hip/hip_runtime.h>

// Complex BatchNorm (training whitening), z:[B=32, N=C*H*W, 2] fp32.
// TRUE single-pass: batch dim split across 4 lane-groups (8 samples/thread,
// 2 positions/thread via float4). Samples retained in registers (32 VGPRs),
// cross-batch moment sums completed with a 4-lane __shfl_xor butterfly.
// Input read exactly once from HBM, output written once.

constexpr int BATCH = 32;
constexpr int BGRP  = 4;             // lane groups covering the batch dim
constexpr int BPER  = BATCH / BGRP;  // 8 batch samples per thread

__global__ __launch_bounds__(256) void cbn_kernel(
    const float4* __restrict__ z,
    const float* __restrict__ gamma,
    const float* __restrict__ beta,
    float4* __restrict__ out,
    int N2)   // N2 = N/2 float4 "pair" positions
{
    const int lane = threadIdx.x & 63;
    const int gwave = (blockIdx.x * blockDim.x + threadIdx.x) >> 6;
    const int p = gwave * 16 + (lane & 15);   // float4 column (2 positions)
    if (p >= N2) return;
    const int g = lane >> 4;                  // which batch-quarter (0..3)

    // ---- load my 8 batch samples (retained: 32 VGPRs) ----
    float4 v[BPER];
#pragma unroll
    for (int k = 0; k < BPER; ++k) {
        v[k] = z[(size_t)(g * BPER + k) * N2 + p];
    }

    // ---- partial raw moments over my 8 samples (both positions) ----
    float sx0 = 0.f, sy0 = 0.f, sxx0 = 0.f, sxy0 = 0.f, syy0 = 0.f;
    float sx1 = 0.f, sy1 = 0.f, sxx1 = 0.f, sxy1 = 0.f, syy1 = 0.f;
#pragma unroll
    for (int k = 0; k < BPER; ++k) {
        float4 q = v[k];
        sx0 += q.x; sy0 += q.y;
        sxx0 = fmaf(q.x, q.x, sxx0);
        sxy0 = fmaf(q.x, q.y, sxy0);
        syy0 = fmaf(q.y, q.y, syy0);
        sx1 += q.z; sy1 += q.w;
        sxx1 = fmaf(q.z, q.z, sxx1);
        sxy1 = fmaf(q.z, q.w, sxy1);
        syy1 = fmaf(q.w, q.w, syy1);
    }

    // ---- complete sums across the 4 b-groups: lanes xor 16, xor 32 ----
#define RED(a) a += __shfl_xor(a, 16); a += __shfl_xor(a, 32);
    RED(sx0) RED(sy0) RED(sxx0) RED(sxy0) RED(syy0)
    RED(sx1) RED(sy1) RED(sxx1) RED(sxy1) RED(syy1)
#undef RED

    const float invB  = 1.0f / BATCH;
    const float invB1 = 1.0f / (BATCH - 1);

    const float g00 = gamma[0], g01 = gamma[1], g10 = gamma[2], g11 = gamma[3];
    const float be0 = beta[0], be1 = beta[1];

    // ---- 2x2 whitening matrix (gamma-fused), position 0 ----
    float mx0 = sx0 * invB, my0 = sy0 * invB;
    float cxx0 = (sxx0 - BATCH * mx0 * mx0) * invB1;
    float cxy0 = (sxy0 - BATCH * mx0 * my0) * invB1;
    float cyy0 = (syy0 - BATCH * my0 * my0) * invB1;
    float s0  = sqrtf(cxx0 * cyy0 - cxy0 * cxy0);
    float rt0 = 1.0f / sqrtf(cxx0 + cyy0 + 2.0f * s0);
    float a00_0 = (cxx0 + s0) * rt0, a01_0 = cxy0 * rt0, a11_0 = (cyy0 + s0) * rt0;
    float c00_0 = g00 * a00_0 + g01 * a01_0;
    float c01_0 = g00 * a01_0 + g01 * a11_0;
    float c10_0 = g10 * a00_0 + g11 * a01_0;
    float c11_0 = g10 * a01_0 + g11 * a11_0;

    // ---- position 1 ----
    float mx1 = sx1 * invB, my1 = sy1 * invB;
    float cxx1 = (sxx1 - BATCH * mx1 * mx1) * invB1;
    float cxy1 = (sxy1 - BATCH * mx1 * my1) * invB1;
    float cyy1 = (syy1 - BATCH * my1 * my1) * invB1;
    float s1  = sqrtf(cxx1 * cyy1 - cxy1 * cxy1);
    float rt1 = 1.0f / sqrtf(cxx1 + cyy1 + 2.0f * s1);
    float a00_1 = (cxx1 + s1) * rt1, a01_1 = cxy1 * rt1, a11_1 = (cyy1 + s1) * rt1;
    float c00_1 = g00 * a00_1 + g01 * a01_1;
    float c01_1 = g00 * a01_1 + g01 * a11_1;
    float c10_1 = g10 * a00_1 + g11 * a01_1;
    float c11_1 = g10 * a01_1 + g11 * a11_1;

    // ---- apply to my retained 8 samples and store ----
#pragma unroll
    for (int k = 0; k < BPER; ++k) {
        float4 q = v[k];
        float dx0 = q.x - mx0, dy0 = q.y - my0;
        float dx1 = q.z - mx1, dy1 = q.w - my1;
        float4 o;
        o.x = fmaf(c00_0, dx0, fmaf(c01_0, dy0, be0));
        o.y = fmaf(c10_0, dx0, fmaf(c11_0, dy0, be1));
        o.z = fmaf(c00_1, dx1, fmaf(c01_1, dy1, be0));
        o.w = fmaf(c10_1, dx1, fmaf(c11_1, dy1, be1));
        out[(size_t)(g * BPER + k) * N2 + p] = o;
    }
}

extern "C" void kernel_launch(void* const* d_in, const int* in_sizes, int n_in,
                              void* d_out, int out_size, void* d_ws, size_t ws_size,
                              hipStream_t stream) {
    const float4* z    = (const float4*)d_in[0];
    const float* gamma = (const float*)d_in[1];
    const float* beta  = (const float*)d_in[2];
    float4* out = (float4*)d_out;

    // in_sizes[0] = B * N * 2; float4 "pair" positions: N2 = N/2
    int N2 = in_sizes[0] / (BATCH * 4);

    // 4 threads per float4 column (batch split), 16 columns per wave.
    long long total_threads = (long long)N2 * BGRP;
    dim3 block(256);
    dim3 grid((unsigned)((total_threads + block.x - 1) / block.x));
    hipLaunchKernelGGL(cbn_kernel, grid, block, 0, stream, z, gamma, beta, out, N2);
}

// Round 5
// 51.362 us; speedup vs baseline: 1.3678x; 1.0523x over previous
//
#include <hip/hip_runtime.h>

// Complex BatchNorm (training whitening), z:[B=32, N=C*H*W, 2] fp32.
// Single-pass, register-retained: batch split across 4 lane-groups
// (8 float4 samples/thread = 32 VGPRs, PINNED via inline asm so the
// compiler cannot rematerialize the loads), cross-group moment reduce
// via __shfl_xor(16/32). Output stored nontemporal (nt) so the write
// stream does not evict the L3-resident input between replays.

constexpr int BATCH = 32;
constexpr int BGRP  = 4;             // lane groups covering the batch dim
constexpr int BPER  = BATCH / BGRP;  // 8 batch samples per thread

typedef float f32x4 __attribute__((ext_vector_type(4)));

__global__ __launch_bounds__(256) void cbn_kernel(
    const float4* __restrict__ z,
    const float* __restrict__ gamma,
    const float* __restrict__ beta,
    float4* __restrict__ out,
    int N2)   // N2 = N/2 float4 "pair" positions
{
    const int lane = threadIdx.x & 63;
    const int gwave = (blockIdx.x * blockDim.x + threadIdx.x) >> 6;
    const int p = gwave * 16 + (lane & 15);   // float4 column (2 positions)
    if (p >= N2) return;
    const int g = lane >> 4;                  // which batch-quarter (0..3)

    // ---- load my 8 batch samples ----
    float4 v[BPER];
#pragma unroll
    for (int k = 0; k < BPER; ++k) {
        v[k] = z[(size_t)(g * BPER + k) * N2 + p];
    }
    // Pin: forbid rematerialization/reload of the samples.
#pragma unroll
    for (int k = 0; k < BPER; ++k) {
        asm volatile("" : "+v"(v[k].x), "+v"(v[k].y), "+v"(v[k].z), "+v"(v[k].w));
    }

    // ---- partial raw moments over my 8 samples (both positions) ----
    float sx0 = 0.f, sy0 = 0.f, sxx0 = 0.f, sxy0 = 0.f, syy0 = 0.f;
    float sx1 = 0.f, sy1 = 0.f, sxx1 = 0.f, sxy1 = 0.f, syy1 = 0.f;
#pragma unroll
    for (int k = 0; k < BPER; ++k) {
        float4 q = v[k];
        sx0 += q.x; sy0 += q.y;
        sxx0 = fmaf(q.x, q.x, sxx0);
        sxy0 = fmaf(q.x, q.y, sxy0);
        syy0 = fmaf(q.y, q.y, syy0);
        sx1 += q.z; sy1 += q.w;
        sxx1 = fmaf(q.z, q.z, sxx1);
        sxy1 = fmaf(q.z, q.w, sxy1);
        syy1 = fmaf(q.w, q.w, syy1);
    }

    // ---- complete sums across the 4 b-groups: lanes xor 16, xor 32 ----
#define RED(a) a += __shfl_xor(a, 16); a += __shfl_xor(a, 32);
    RED(sx0) RED(sy0) RED(sxx0) RED(sxy0) RED(syy0)
    RED(sx1) RED(sy1) RED(sxx1) RED(sxy1) RED(syy1)
#undef RED

    const float invB  = 1.0f / BATCH;
    const float invB1 = 1.0f / (BATCH - 1);

    const float g00 = gamma[0], g01 = gamma[1], g10 = gamma[2], g11 = gamma[3];
    const float be0 = beta[0], be1 = beta[1];

    // ---- 2x2 whitening matrix (gamma-fused), position 0 ----
    float mx0 = sx0 * invB, my0 = sy0 * invB;
    float cxx0 = (sxx0 - BATCH * mx0 * mx0) * invB1;
    float cxy0 = (sxy0 - BATCH * mx0 * my0) * invB1;
    float cyy0 = (syy0 - BATCH * my0 * my0) * invB1;
    float s0  = sqrtf(cxx0 * cyy0 - cxy0 * cxy0);
    float rt0 = 1.0f / sqrtf(cxx0 + cyy0 + 2.0f * s0);
    float a00_0 = (cxx0 + s0) * rt0, a01_0 = cxy0 * rt0, a11_0 = (cyy0 + s0) * rt0;
    float c00_0 = g00 * a00_0 + g01 * a01_0;
    float c01_0 = g00 * a01_0 + g01 * a11_0;
    float c10_0 = g10 * a00_0 + g11 * a01_0;
    float c11_0 = g10 * a01_0 + g11 * a11_0;

    // ---- position 1 ----
    float mx1 = sx1 * invB, my1 = sy1 * invB;
    float cxx1 = (sxx1 - BATCH * mx1 * mx1) * invB1;
    float cxy1 = (sxy1 - BATCH * mx1 * my1) * invB1;
    float cyy1 = (syy1 - BATCH * my1 * my1) * invB1;
    float s1  = sqrtf(cxx1 * cyy1 - cxy1 * cxy1);
    float rt1 = 1.0f / sqrtf(cxx1 + cyy1 + 2.0f * s1);
    float a00_1 = (cxx1 + s1) * rt1, a01_1 = cxy1 * rt1, a11_1 = (cyy1 + s1) * rt1;
    float c00_1 = g00 * a00_1 + g01 * a01_1;
    float c01_1 = g00 * a01_1 + g01 * a11_1;
    float c10_1 = g10 * a00_1 + g11 * a01_1;
    float c11_1 = g10 * a01_1 + g11 * a11_1;

    // ---- apply to my retained 8 samples and store (nontemporal) ----
#pragma unroll
    for (int k = 0; k < BPER; ++k) {
        float4 q = v[k];
        float dx0 = q.x - mx0, dy0 = q.y - my0;
        float dx1 = q.z - mx1, dy1 = q.w - my1;
        f32x4 o;
        o.x = fmaf(c00_0, dx0, fmaf(c01_0, dy0, be0));
        o.y = fmaf(c10_0, dx0, fmaf(c11_0, dy0, be1));
        o.z = fmaf(c00_1, dx1, fmaf(c01_1, dy1, be0));
        o.w = fmaf(c10_1, dx1, fmaf(c11_1, dy1, be1));
        __builtin_nontemporal_store(o,
            (f32x4*)&out[(size_t)(g * BPER + k) * N2 + p]);
    }
}

extern "C" void kernel_launch(void* const* d_in, const int* in_sizes, int n_in,
                              void* d_out, int out_size, void* d_ws, size_t ws_size,
                              hipStream_t stream) {
    const float4* z    = (const float4*)d_in[0];
    const float* gamma = (const float*)d_in[1];
    const float* beta  = (const float*)d_in[2];
    float4* out = (float4*)d_out;

    // in_sizes[0] = B * N * 2; float4 "pair" positions: N2 = N/2
    int N2 = in_sizes[0] / (BATCH * 4);

    // 4 threads per float4 column (batch split), 16 columns per wave.
    long long total_threads = (long long)N2 * BGRP;
    dim3 block(256);
    dim3 grid((unsigned)((total_threads + block.x - 1) / block.x));
    hipLaunchKernelGGL(cbn_kernel, grid, block, 0, stream, z, gamma, beta, out, N2);
}

// Round 6
// 49.713 us; speedup vs baseline: 1.4131x; 1.0332x over previous
//
#include <hip/hip_runtime.h>

// Complex BatchNorm (training whitening), z:[B=32, N=C*H*W, 2] fp32.
// R1 structure (1 thread = 1 position, 32 float2 samples) + forced register
// retention (inline-asm pin, verified effective in R5) + nontemporal stores
// (protect input L3 residency). No cross-lane ops; 32 loads in flight per
// thread; 512B contiguous per-wave segments.

constexpr int BATCH = 32;

typedef float f32x2 __attribute__((ext_vector_type(2)));

__global__ __launch_bounds__(256) void cbn_kernel(
    const float2* __restrict__ z,
    const float* __restrict__ gamma,
    const float* __restrict__ beta,
    float2* __restrict__ out,
    int N)
{
    int n = blockIdx.x * blockDim.x + threadIdx.x;
    if (n >= N) return;

    // ---- load all 32 batch samples (64 VGPRs of data) ----
    float2 v[BATCH];
#pragma unroll
    for (int b = 0; b < BATCH; ++b) {
        v[b] = z[(size_t)b * N + n];
    }
    // Pin: forbid rematerialization/reload (compiler otherwise re-reads
    // global 3x; verified retained in R5 via VGPR count).
#pragma unroll
    for (int b = 0; b < BATCH; ++b) {
        asm volatile("" : "+v"(v[b].x), "+v"(v[b].y));
    }

    // ---- raw moments ----
    float sx = 0.f, sy = 0.f, sxx = 0.f, sxy = 0.f, syy = 0.f;
#pragma unroll
    for (int b = 0; b < BATCH; ++b) {
        float2 q = v[b];
        sx += q.x; sy += q.y;
        sxx = fmaf(q.x, q.x, sxx);
        sxy = fmaf(q.x, q.y, sxy);
        syy = fmaf(q.y, q.y, syy);
    }

    const float invB  = 1.0f / BATCH;
    const float invB1 = 1.0f / (BATCH - 1);

    float mx = sx * invB, my = sy * invB;
    float cxx = (sxx - BATCH * mx * mx) * invB1;
    float cxy = (sxy - BATCH * mx * my) * invB1;
    float cyy = (syy - BATCH * my * my) * invB1;

    float s  = sqrtf(cxx * cyy - cxy * cxy);
    float rt = 1.0f / sqrtf(cxx + cyy + 2.0f * s);
    float a00 = (cxx + s) * rt;
    float a01 = cxy * rt;           // symmetric
    float a11 = (cyy + s) * rt;

    const float g00 = gamma[0], g01 = gamma[1], g10 = gamma[2], g11 = gamma[3];
    const float be0 = beta[0], be1 = beta[1];

    float c00 = g00 * a00 + g01 * a01;
    float c01 = g00 * a01 + g01 * a11;
    float c10 = g10 * a00 + g11 * a01;
    float c11 = g10 * a01 + g11 * a11;

    // ---- apply to retained samples, nontemporal store ----
#pragma unroll
    for (int b = 0; b < BATCH; ++b) {
        float dx = v[b].x - mx;
        float dy = v[b].y - my;
        f32x2 o;
        o.x = fmaf(c00, dx, fmaf(c01, dy, be0));
        o.y = fmaf(c10, dx, fmaf(c11, dy, be1));
        __builtin_nontemporal_store(o, (f32x2*)&out[(size_t)b * N + n]);
    }
}

extern "C" void kernel_launch(void* const* d_in, const int* in_sizes, int n_in,
                              void* d_out, int out_size, void* d_ws, size_t ws_size,
                              hipStream_t stream) {
    const float2* z    = (const float2*)d_in[0];
    const float* gamma = (const float*)d_in[1];
    const float* beta  = (const float*)d_in[2];
    float2* out = (float2*)d_out;

    int N = in_sizes[0] / (BATCH * 2);

    dim3 block(256);
    dim3 grid((N + block.x - 1) / block.x);
    hipLaunchKernelGGL(cbn_kernel, grid, block, 0, stream, z, gamma, beta, out, N);
}